// Round 10
// baseline (939.693 us; speedup 1.0000x reference)
//
#include <hip/hip_runtime.h>

typedef _Float16 f16x8 __attribute__((ext_vector_type(8)));
typedef float f32x4 __attribute__((ext_vector_type(4)));

#define Dd 256
#define Hh 1024

// ---------- prep: pack weights fragment-major for 16-wave consumption ----------
// W1P tile (w,nt,kk) = (w*4+nt)*8+kk, w:0..15, nt:0..3, kk:0..7.
// lane(q*16+ln)*8+j holds W1[kk*32+q*8+j][w*64+nt*16+ln] (B-frag 16x16x32).
__global__ void pack_w1_kernel(const float* __restrict__ W1, _Float16* __restrict__ W1P) {
    int gid = blockIdx.x * 256 + threadIdx.x;       // 256*1024 elements
    int h = gid & 1023, d = gid >> 10;
    int w = h >> 6, nt = (h >> 4) & 3, ln = h & 15;
    int kk = d >> 5, q = (d >> 3) & 3, j = d & 7;
    W1P[(((w * 4 + nt) * 8 + kk) * 64 + q * 16 + ln) * 8 + j] = (_Float16)W1[d * 1024 + h];
}
// W2P tile (w,kk) = w*32+kk, w:0..15, kk:0..31.
// lane(q*16+ln)*8+j holds W2[kk*32+q*8+j][w*16+ln].
__global__ void pack_w2_kernel(const float* __restrict__ W2, _Float16* __restrict__ W2P) {
    int gid = blockIdx.x * 256 + threadIdx.x;       // 1024*256 elements
    int dcol = gid & 255, hrow = gid >> 8;
    int w = dcol >> 4, ln = dcol & 15;
    int kk = hrow >> 5, q = (hrow >> 3) & 3, j = hrow & 7;
    W2P[((w * 32 + kk) * 64 + q * 16 + ln) * 8 + j] = (_Float16)W2[hrow * 256 + dcol];
}

// raw 16B global load via 64-bit vaddr; opaque to compiler waitcnt tracking —
// correctness is OUR vmcnt discipline (validated bit-exact in round 9).
__device__ __forceinline__ void gload(f16x8& dst, const _Float16* addr) {
    asm volatile("global_load_dwordx4 %0, %1, off"
                 : "=v"(dst) : "v"(addr) : "memory");
}
// gate: oldest of 16 outstanding retired; ties v so consuming MFMA can't hoist.
__device__ __forceinline__ void wait15(f16x8& v) {
    asm volatile("s_waitcnt vmcnt(15)" : "+v"(v) :: "memory");
}
// LDS-only barrier: drains DS ops but leaves the weight ring in flight.
__device__ __forceinline__ void barrier_lgkm() {
    asm volatile("s_waitcnt lgkmcnt(0)\n\ts_barrier" ::: "memory");
}

// ---------------- main: 64 blocks x 1024 thr (16 waves), register weight ring ----
// Round-9 post-mortem: per-wave vmem throughput is a hard ~7-9 GB/s (matches
// m56's 36.9 TB/s / 4096 waves). Fix: halve per-wave weight bytes by doubling
// waves per block. Wave w owns H-slice [w*64,+64) (GEMM1: tiles 0..31) and
// D-slice [w*16,+16) (GEMM2: tiles 32..63); 64 KB/wave/eval. Perpetual 16-slot
// VGPR ring, in flight across barriers and eval boundaries. Weights never
// touch LDS. Zero inter-block communication.
__global__ __launch_bounds__(1024, 4) void ode_kernel(
    const float* __restrict__ z0, const float* __restrict__ tv,
    const float* __restrict__ b1, const float* __restrict__ b2,
    const _Float16* __restrict__ W1P, const _Float16* __restrict__ W2P,
    float* __restrict__ out) {
    __shared__ _Float16 act_lds[16][1032];   // 33 KB (+8 pad)
    __shared__ _Float16 z_lds[16][264];      // 8.25 KB

    const int tid  = threadIdx.x;
    const int w    = tid >> 6;        // wave 0..15
    const int lane = tid & 63;
    const int ln   = lane & 15;
    const int q    = lane >> 4;
    const int m0   = blockIdx.x * 16;

    const float h = (tv[1] - tv[0]) * 0.125f;

    float bb1[4];
#pragma unroll
    for (int nt = 0; nt < 4; ++nt) bb1[nt] = b1[w * 64 + nt * 16 + ln];
    const float bb2 = b2[w * 16 + ln];

    // per-lane stream bases: wave-slice origin + lane's 16B within a tile
    const _Float16* W1l = W1P + (size_t)(w * 32) * 512 + lane * 8;  // tiles 0..31
    const _Float16* W2l = W2P + (size_t)(w * 32) * 512 + lane * 8;  // tiles 32..63

    f16x8 buf[16];   // landing ring: 64 VGPRs

#define ISSUE_TILE(slot, ti) do {                                               \
        const _Float16* _p = ((ti) < 32) ? (W1l + (size_t)(ti) * 512)           \
                                         : (W2l + (size_t)((ti) - 32) * 512);   \
        gload(buf[slot], _p);                                                   \
    } while (0)

    // RK4 state (C-layout): z[r] = z[m0+q*4+r][w*16+ln]
    f32x4 z, zsum;
#pragma unroll
    for (int r = 0; r < 4; ++r)
        z[r] = z0[(m0 + q * 4 + r) * Dd + w * 16 + ln];
#pragma unroll
    for (int r = 0; r < 4; ++r)
        z_lds[q * 4 + r][w * 16 + ln] = (_Float16)z[r];
    __syncthreads();   // full barrier OK: ring not yet primed

    // prime the perpetual ring: tiles 0..15
#pragma unroll
    for (int p = 0; p < 16; ++p) ISSUE_TILE(p, p);

#pragma unroll 1
    for (int ev = 0; ev < 32; ++ev) {
        const int e = ev & 3;

        // ---- GEMM1: act[:, w*64..+64) = tanh(z @ W1 + b1), tiles i=0..31 ----
        f16x8 a1[8];
#pragma unroll
        for (int kk = 0; kk < 8; ++kk)
            a1[kk] = *(const f16x8*)&z_lds[ln][kk * 32 + q * 8];

#pragma unroll
        for (int nt = 0; nt < 4; ++nt) {
            f32x4 acc = {0.f, 0.f, 0.f, 0.f};
#pragma unroll
            for (int kk = 0; kk < 8; ++kk) {
                const int i = nt * 8 + kk, s = i & 15;
                wait15(buf[s]);
                acc = __builtin_amdgcn_mfma_f32_16x16x32_f16(a1[kk], buf[s], acc, 0, 0, 0);
                ISSUE_TILE(s, (i + 16) & 63);
            }
#pragma unroll
            for (int r = 0; r < 4; ++r) {
                float x = acc[r] + bb1[nt];
                float ex = __expf(2.0f * x);
                act_lds[q * 4 + r][w * 64 + nt * 16 + ln] =
                    (_Float16)(1.0f - 2.0f / (ex + 1.0f));
            }
        }
        barrier_lgkm();   // act visible; weight ring stays in flight

        // ---- GEMM2: k[:, w*16..+16) = act @ W2 + b2, tiles i=32..63 ----
        f32x4 acc2 = {0.f, 0.f, 0.f, 0.f};
        f16x8 a2r[4];   // 2-ahead a2 prefetch ring
        a2r[0] = *(const f16x8*)&act_lds[ln][0 * 32 + q * 8];
        a2r[1] = *(const f16x8*)&act_lds[ln][1 * 32 + q * 8];
#pragma unroll
        for (int kk = 0; kk < 32; ++kk) {
            if (kk + 2 < 32)
                a2r[(kk + 2) & 3] = *(const f16x8*)&act_lds[ln][(kk + 2) * 32 + q * 8];
            const int i = 32 + kk, s = i & 15;
            wait15(buf[s]);
            acc2 = __builtin_amdgcn_mfma_f32_16x16x32_f16(a2r[kk & 3], buf[s], acc2, 0, 0, 0);
            ISSUE_TILE(s, (i + 16) & 63);   // i>=48 prefetches next eval's tiles 0..15
        }

        // ---- RK4 epilogue (registers) ----
        f32x4 kv, za;
#pragma unroll
        for (int r = 0; r < 4; ++r) kv[r] = acc2[r] + bb2;
        if (e == 0) {
            zsum = kv;
        } else if (e == 3) {
#pragma unroll
            for (int r = 0; r < 4; ++r) zsum[r] += kv[r];
        } else {
#pragma unroll
            for (int r = 0; r < 4; ++r) zsum[r] += 2.0f * kv[r];
        }
        if (e < 3) {
            const float c = (e == 2) ? h : 0.5f * h;
#pragma unroll
            for (int r = 0; r < 4; ++r) za[r] = z[r] + c * kv[r];
        } else {
#pragma unroll
            for (int r = 0; r < 4; ++r) { z[r] += (h * (1.0f / 6.0f)) * zsum[r]; za[r] = z[r]; }
        }
#pragma unroll
        for (int r = 0; r < 4; ++r)
            z_lds[q * 4 + r][w * 16 + ln] = (_Float16)za[r];
        barrier_lgkm();   // z visible; ring still in flight into next eval
    }

    // drain the ring before endpgm
    asm volatile("s_waitcnt vmcnt(0)" ::: "memory");

#pragma unroll
    for (int r = 0; r < 4; ++r)
        out[(m0 + q * 4 + r) * Dd + w * 16 + ln] = z[r];
#undef ISSUE_TILE
}

extern "C" void kernel_launch(void* const* d_in, const int* in_sizes, int n_in,
                              void* d_out, int out_size, void* d_ws, size_t ws_size,
                              hipStream_t stream) {
    const float* z0 = (const float*)d_in[0];
    const float* tv = (const float*)d_in[1];
    const float* W1 = (const float*)d_in[2];   // [256][1024]
    const float* b1 = (const float*)d_in[3];   // [1024]
    const float* W2 = (const float*)d_in[4];   // [1024][256]
    const float* b2 = (const float*)d_in[5];   // [256]
    float* out = (float*)d_out;

    _Float16* W1P = (_Float16*)d_ws;           // 512 KB fragment-major
    _Float16* W2P = W1P + Hh * Dd;             // 512 KB fragment-major

    pack_w1_kernel<<<1024, 256, 0, stream>>>(W1, W1P);
    pack_w2_kernel<<<1024, 256, 0, stream>>>(W2, W2P);

    ode_kernel<<<64, 1024, 0, stream>>>(z0, tv, b1, b2, W1P, W2P, out);
}

// Round 12
// 655.353 us; speedup vs baseline: 1.4339x; 1.4339x over previous
//
#include <hip/hip_runtime.h>

typedef _Float16 f16x8 __attribute__((ext_vector_type(8)));
typedef float f32x4 __attribute__((ext_vector_type(4)));

#define Dd 256
#define Hh 1024

// ---------- prep: pack weights fragment-major (bit-exact validated R7/R9) ----------
// W1P tile (w,nt,kk) = (w*8+nt)*8+kk, w:0..7. lane(q*16+ln)*8+j holds
//   W1[kk*32+q*8+j][w*128+nt*16+ln]  (B-fragment for 16x16x32 MFMA)
__global__ void pack_w1_kernel(const float* __restrict__ W1, _Float16* __restrict__ W1P) {
    int gid = blockIdx.x * 256 + threadIdx.x;       // 256*1024 elements
    int h = gid & 1023, d = gid >> 10;
    int w = h >> 7, nt = (h >> 4) & 7, ln = h & 15;
    int kk = d >> 5, q = (d >> 3) & 3, j = d & 7;
    W1P[(((w * 8 + nt) * 8 + kk) * 64 + q * 16 + ln) * 8 + j] = (_Float16)W1[d * 1024 + h];
}
// W2P tile (w,kk,t) = ((w*32+kk)*2+t), w:0..7
__global__ void pack_w2_kernel(const float* __restrict__ W2, _Float16* __restrict__ W2P) {
    int gid = blockIdx.x * 256 + threadIdx.x;       // 1024*256 elements
    int dcol = gid & 255, hrow = gid >> 8;
    int w = dcol >> 5, t = (dcol >> 4) & 1, ln = dcol & 15;
    int kk = hrow >> 5, q = (hrow >> 3) & 3, j = hrow & 7;
    W2P[(((w * 32 + kk) * 2 + t) * 64 + q * 16 + ln) * 8 + j] = (_Float16)W2[hrow * 256 + dcol];
}

typedef __attribute__((address_space(1))) const unsigned int gu32;
typedef __attribute__((address_space(3))) unsigned int lu32;

// async 1KB tile: global (g is WAVE-UNIFORM tile base; lane*16B added HERE and
// ONLY here — R11's bug was a second lane*8 baked into the stream base) ->
// LDS (uniform base, HW lane-scatter).
__device__ __forceinline__ void async_tile(const _Float16* g, _Float16* l, int lane) {
    __builtin_amdgcn_global_load_lds((gu32*)(g + lane * 8), (lu32*)l, 16, 0, 0);
}
// raw 16B global load -> VGPR quad (vaddr form; R9-validated)
__device__ __forceinline__ void gload(f16x8& dst, const _Float16* addr) {
    asm volatile("global_load_dwordx4 %0, %1, off" : "=v"(dst) : "v"(addr) : "memory");
}
// vmcnt gate tying a ring slot (consuming MFMA cannot hoist above)
__device__ __forceinline__ void wait15t(f16x8& v) {
    asm volatile("s_waitcnt vmcnt(15)" : "+v"(v) :: "memory");
}
// zero-cost scheduling tie (slot proven-landed by an earlier vmcnt(0))
__device__ __forceinline__ void tie(f16x8& v) { asm volatile("" : "+v"(v)); }
// LDS-only barrier: leaves vmem (both weight streams) in flight
__device__ __forceinline__ void barrier_lgkm() {
    asm volatile("s_waitcnt lgkmcnt(0)\n\ts_barrier" ::: "memory");
}
#define WAITN(n) asm volatile("s_waitcnt vmcnt(" #n ")" ::: "memory")

// ---------------- main: 64 blocks x 512 thr, DUAL weight paths ----------------
// Block owns 16 batch rows, whole solve, zero inter-block sync. Wave w owns
// H-slice [w*128,+128) and D-slice [w*32,+32). Per eval per wave: W1 64 KB via
// LDS-DMA 3-slot ring (16 chunks x 4KB, R7 path), W2 64 KB via 16-slot VGPR
// ring (64 tiles x 1KB, R9 path) — both in flight simultaneously on different
// return paths, one shared vmcnt with exact static accounting (in-order/FIFO
// retirement, m135; extra compiler vmem only makes waits stricter — suffix
// argument). Next-eval W2 tiles 0..15 + W1 chunks 0..2 issue during GEMM2's
// tail in a fixed mirror order; GEMM1 head waits (18/14/10) match it.
__global__ __launch_bounds__(512, 2) void ode_kernel(
    const float* __restrict__ z0, const float* __restrict__ tv,
    const float* __restrict__ b1, const float* __restrict__ b2,
    const _Float16* __restrict__ W1P, const _Float16* __restrict__ W2P,
    float* __restrict__ out) {
    __shared__ _Float16 wbuf[8][3][2048];    // 96 KB: per-wave W1 DMA ring
    __shared__ _Float16 act_lds[16][1032];   // 33 KB
    __shared__ _Float16 z_lds[16][264];      // 8.25 KB

    const int tid  = threadIdx.x;
    const int w    = tid >> 6;
    const int lane = tid & 63;
    const int ln   = lane & 15;
    const int q    = lane >> 4;
    const int m0   = blockIdx.x * 16;

    const float h = (tv[1] - tv[0]) * 0.125f;

    float bb1[8];
#pragma unroll
    for (int nt = 0; nt < 8; ++nt) bb1[nt] = b1[w * 128 + nt * 16 + ln];
    float bb2v[2];
#pragma unroll
    for (int t = 0; t < 2; ++t) bb2v[t] = b2[w * 32 + t * 16 + ln];

    // DMA stream base: wave-uniform (lane offset added inside async_tile ONLY)
    const _Float16* W1dma = W1P + (size_t)(w * 64) * 512;             // chunks 0..15 (4KB)
    // register stream base: per-lane (gload takes the final address)
    const _Float16* W2l   = W2P + (size_t)(w * 64) * 512 + lane * 8;  // tiles 0..63 (1KB)

    f16x8 buf[16];   // W2 landing ring: 64 VGPRs

#define ISSUE_R(slot, ti) gload(buf[slot], W2l + (size_t)(ti) * 512)
#define ISSUE_D(cc) do { asm volatile("s_waitcnt lgkmcnt(0)" ::: "memory");      \
        const _Float16* _g = W1dma + (size_t)(cc) * 2048;                        \
        _Float16* _l = &wbuf[w][(cc) % 3][0];                                    \
        _Pragma("unroll")                                                        \
        for (int _i = 0; _i < 4; ++_i) async_tile(_g + _i * 512, _l + _i * 512, lane); \
    } while (0)

    // RK4 state (C-layout): z[t][r] = z[m0+q*4+r][w*32+t*16+ln]
    f32x4 z[2], zsum[2];
#pragma unroll
    for (int t = 0; t < 2; ++t)
#pragma unroll
        for (int r = 0; r < 4; ++r)
            z[t][r] = z0[(m0 + q * 4 + r) * Dd + w * 32 + t * 16 + ln];
#pragma unroll
    for (int t = 0; t < 2; ++t)
#pragma unroll
        for (int r = 0; r < 4; ++r)
            z_lds[q * 4 + r][w * 32 + t * 16 + ln] = (_Float16)z[t][r];
    __syncthreads();   // drains vmcnt: clean slate for static accounting

    // ---- prime (exact mirror of the eval-tail order) ----
    ISSUE_R(0, 0); ISSUE_R(1, 1); ISSUE_R(2, 2); ISSUE_R(3, 3); ISSUE_R(4, 4); ISSUE_R(5, 5);
    ISSUE_D(0);
    ISSUE_R(6, 6); ISSUE_R(7, 7); ISSUE_R(8, 8); ISSUE_R(9, 9);
    ISSUE_D(1);
    ISSUE_R(10, 10); ISSUE_R(11, 11); ISSUE_R(12, 12); ISSUE_R(13, 13);
    ISSUE_D(2);
    ISSUE_R(14, 14); ISSUE_R(15, 15);

#pragma unroll 1
    for (int ev = 0; ev < 32; ++ev) {
        const int e = ev & 3;

        // ---- GEMM1: act = tanh(z @ W1 + b1); W1 chunks 0..15 from DMA ring ----
        f16x8 a1[8];
#pragma unroll
        for (int kk = 0; kk < 8; ++kk)
            a1[kk] = *(const f16x8*)&z_lds[ln][kk * 32 + q * 8];

#pragma unroll
        for (int nt = 0; nt < 8; ++nt) {
            f32x4 acc = {0.f, 0.f, 0.f, 0.f};
#pragma unroll
            for (int hf = 0; hf < 2; ++hf) {
                const int c = nt * 2 + hf;   // chunk c: tiles kk = hf*4..+3
                // issued-after counts: c0:18 c1:14 c2:10 c3..13:8 c14:4 c15:0
                if (c == 0) WAITN(18);
                else if (c == 1) WAITN(14);
                else if (c == 2) WAITN(10);
                else if (c <= 13) WAITN(8);
                else if (c == 14) WAITN(4);
                else WAITN(0);               // also retires W2 tiles 0..15 (older)
                const _Float16* tb = &wbuf[w][c % 3][0];
#pragma unroll
                for (int i = 0; i < 4; ++i) {
                    f16x8 bf = *(const f16x8*)&tb[i * 512 + lane * 8];
                    acc = __builtin_amdgcn_mfma_f32_16x16x32_f16(a1[hf * 4 + i], bf, acc, 0, 0, 0);
                }
                if (c + 3 <= 15) ISSUE_D(c + 3);
            }
#pragma unroll
            for (int r = 0; r < 4; ++r) {
                float x = acc[r] + bb1[nt];
                float ex = __expf(2.0f * x);
                act_lds[q * 4 + r][w * 128 + nt * 16 + ln] =
                    (_Float16)(1.0f - 2.0f / (ex + 1.0f));
            }
        }
        barrier_lgkm();   // act visible; vmem streams stay in flight

        // ---- GEMM2: k = act @ W2 + b2; W2 tiles 0..63 from VGPR ring ----
        f32x4 acc2[2] = {{0.f, 0.f, 0.f, 0.f}, {0.f, 0.f, 0.f, 0.f}};
        f16x8 a2r[4];
        a2r[0] = *(const f16x8*)&act_lds[ln][0 * 32 + q * 8];
        a2r[1] = *(const f16x8*)&act_lds[ln][1 * 32 + q * 8];
#pragma unroll
        for (int i = 0; i < 64; ++i) {
            const int kk = i >> 1, t = i & 1, s = i & 15;
            if (t == 0 && kk + 2 < 32)
                a2r[(kk + 2) & 3] = *(const f16x8*)&act_lds[ln][(kk + 2) * 32 + q * 8];
            if (i < 16) tie(buf[s]);        // landed (GEMM1's vmcnt(0)); pin order
            else        wait15t(buf[s]);    // >=15 ring issues after it
            acc2[t] = __builtin_amdgcn_mfma_f32_16x16x32_f16(a2r[kk & 3], buf[s], acc2[t], 0, 0, 0);
            if (i < 48) ISSUE_R(s, i + 16);      // this eval's tiles 16..63
            else        ISSUE_R(s, i - 48);      // next eval's tiles 0..15
            if (i == 53) ISSUE_D(0);             // next eval's W1 chunks
            else if (i == 57) ISSUE_D(1);
            else if (i == 61) ISSUE_D(2);
        }

        // ---- RK4 epilogue (registers) ----
#pragma unroll
        for (int t = 0; t < 2; ++t) {
            f32x4 kv, za;
#pragma unroll
            for (int r = 0; r < 4; ++r) kv[r] = acc2[t][r] + bb2v[t];
            if (e == 0) {
                zsum[t] = kv;
            } else if (e == 3) {
#pragma unroll
                for (int r = 0; r < 4; ++r) zsum[t][r] += kv[r];
            } else {
#pragma unroll
                for (int r = 0; r < 4; ++r) zsum[t][r] += 2.0f * kv[r];
            }
            if (e < 3) {
                const float c = (e == 2) ? h : 0.5f * h;
#pragma unroll
                for (int r = 0; r < 4; ++r) za[r] = z[t][r] + c * kv[r];
            } else {
#pragma unroll
                for (int r = 0; r < 4; ++r) {
                    z[t][r] += (h * (1.0f / 6.0f)) * zsum[t][r];
                    za[r] = z[t][r];
                }
            }
#pragma unroll
            for (int r = 0; r < 4; ++r)
                z_lds[q * 4 + r][w * 32 + t * 16 + ln] = (_Float16)za[r];
        }
        barrier_lgkm();   // z visible; streams still in flight into next eval
    }

    asm volatile("s_waitcnt vmcnt(0)" ::: "memory");   // drain before endpgm

#pragma unroll
    for (int t = 0; t < 2; ++t)
#pragma unroll
        for (int r = 0; r < 4; ++r)
            out[(m0 + q * 4 + r) * Dd + w * 32 + t * 16 + ln] = z[t][r];
#undef ISSUE_R
#undef ISSUE_D
}

extern "C" void kernel_launch(void* const* d_in, const int* in_sizes, int n_in,
                              void* d_out, int out_size, void* d_ws, size_t ws_size,
                              hipStream_t stream) {
    const float* z0 = (const float*)d_in[0];
    const float* tv = (const float*)d_in[1];
    const float* W1 = (const float*)d_in[2];   // [256][1024]
    const float* b1 = (const float*)d_in[3];   // [1024]
    const float* W2 = (const float*)d_in[4];   // [1024][256]
    const float* b2 = (const float*)d_in[5];   // [256]
    float* out = (float*)d_out;

    _Float16* W1P = (_Float16*)d_ws;           // 512 KB fragment-major
    _Float16* W2P = W1P + Hh * Dd;             // 512 KB fragment-major

    pack_w1_kernel<<<1024, 256, 0, stream>>>(W1, W1P);
    pack_w2_kernel<<<1024, 256, 0, stream>>>(W2, W2P);

    ode_kernel<<<64, 512, 0, stream>>>(z0, tv, b1, b2, W1P, W2P, out);
}